// Round 3
// baseline (218.846 us; speedup 1.0000x reference)
//
#include <hip/hip_runtime.h>

// YOLOv1 loss: pred/label (16384, 30, 7, 7) fp32 -> scalar.
// R2: LDS staging. R0/R1 were latency-bound (VGPR=32 forced serialized
// strided loads; 74us, VALUBusy 8.5%, HBM 19%). Stage 4 batches/block as
// contiguous float4 global->LDS copies (independent, fully pipelined),
// then compute from LDS.

#define NBATCH 16384
#define NCH 30
#define NCELL 49       // 7*7
#define BSTRIDE 1470   // 30*49
#define BLOCK 256
#define NB 4           // batches per block
#define CHUNK (NB * BSTRIDE)   // 5880 floats per tensor per block
#define CHUNK4 (CHUNK / 4)     // 1470 float4 (exact)

__device__ __forceinline__ float sq(float x) { return x * x; }

__device__ __forceinline__ float iou_vs_label(float x, float y, float w, float h,
                                              float fc, float fr,
                                              float lx1, float ly1, float lx2, float ly2,
                                              float larea) {
    const float inv7 = 1.0f / 7.0f;
    float cx = (x + fc) * inv7;
    float cy = (y + fr) * inv7;
    float hw = w * 0.5f, hh = h * 0.5f;
    float x1 = cx - hw, y1 = cy - hh;
    float x2 = cx + hw, y2 = cy + hh;
    float iw = fmaxf(fminf(x2, lx2) - fmaxf(x1, lx1), 0.0f);
    float ih = fmaxf(fminf(y2, ly2) - fmaxf(y1, ly1), 0.0f);
    float inter = iw * ih;
    float area = (x2 - x1) * (y2 - y1);
    return inter / (area + larea - inter + 1e-10f);
}

__global__ __launch_bounds__(BLOCK) void yolo_loss_kernel(const float* __restrict__ pred,
                                                          const float* __restrict__ label,
                                                          float* __restrict__ out) {
    __shared__ float4 sp4[CHUNK4];
    __shared__ float4 sl4[CHUNK4];

    const int blk = blockIdx.x;

    // ---- Stage: contiguous, coalesced, fully independent float4 copies ----
    {
        const float4* gp = (const float4*)(pred + (size_t)blk * CHUNK);
        const float4* gl = (const float4*)(label + (size_t)blk * CHUNK);
#pragma unroll
        for (int it = 0; it < 6; ++it) {
            int i = it * BLOCK + threadIdx.x;
            if (i < CHUNK4) {
                sp4[i] = gp[i];
                sl4[i] = gl[i];
            }
        }
    }
    __syncthreads();

    // ---- Compute: 196 threads = 4 batches x 49 cells, reads from LDS ----
    float per_cell = 0.0f;
    if (threadIdx.x < NB * NCELL) {
        const int lb = threadIdx.x / NCELL;
        const int rc = threadIdx.x - lb * NCELL;
        const int r = rc / 7;
        const int c = rc - r * 7;

        const float* sp = (const float*)sp4 + lb * BSTRIDE + rc;
        const float* sl = (const float*)sl4 + lb * BSTRIDE + rc;

        float p[NCH], l[NCH];
#pragma unroll
        for (int ch = 0; ch < NCH; ++ch) {
            p[ch] = sp[ch * NCELL];
            l[ch] = sl[ch * NCELL];
        }

        const float fc = (float)c, fr = (float)r;
        const float inv7 = 1.0f / 7.0f;

        float lcx = (l[0] + fc) * inv7;
        float lcy = (l[1] + fr) * inv7;
        float lhw = l[2] * 0.5f, lhh = l[3] * 0.5f;
        float lx1 = lcx - lhw, ly1 = lcy - lhh;
        float lx2 = lcx + lhw, ly2 = lcy + lhh;
        float larea = (lx2 - lx1) * (ly2 - ly1);

        float iou1 = iou_vs_label(p[0], p[1], p[2], p[3], fc, fr, lx1, ly1, lx2, ly2, larea);
        float iou2 = iou_vs_label(p[5], p[6], p[7], p[8], fc, fr, lx1, ly1, lx2, ly2, larea);
        bool choose1 = iou1 >= iou2;

        float coord1 = 5.0f * (sq(p[0] - l[0]) + sq(p[1] - l[1]))
                     + sq(sqrtf(p[2]) - sqrtf(l[2])) + sq(sqrtf(p[3]) - sqrtf(l[3]));
        float coord2 = 5.0f * (sq(p[5] - l[5]) + sq(p[6] - l[6]))
                     + sq(sqrtf(p[7]) - sqrtf(l[7])) + sq(sqrtf(p[8]) - sqrtf(l[8]));

        float obj1 = sq(p[4] - iou1);
        float obj2 = sq(p[9] - iou2);

        float coord      = choose1 ? coord1 : coord2;
        float obj_conf   = choose1 ? obj1 : obj2;
        float noobj_conf = 0.5f * (choose1 ? obj2 : obj1);

        float class_l = 0.0f;
#pragma unroll
        for (int ch = 10; ch < NCH; ++ch) class_l += sq(p[ch] - l[ch]);

        float obj_cell = coord + obj_conf + noobj_conf + class_l;
        float psum = p[4] + p[9];
        float noobj_cell = 0.5f * psum * psum;

        per_cell = (l[4] == 1.0f) ? obj_cell : noobj_cell;
    }

    // ---- Reduce: wave shuffle -> LDS -> one atomic per block ----
    float v = per_cell;
#pragma unroll
    for (int off = 32; off > 0; off >>= 1) v += __shfl_down(v, off, 64);

    __shared__ float smem[BLOCK / 64];
    const int lane = threadIdx.x & 63;
    const int wave = threadIdx.x >> 6;
    if (lane == 0) smem[wave] = v;
    __syncthreads();
    if (threadIdx.x == 0) {
        float s = smem[0] + smem[1] + smem[2] + smem[3];
        atomicAdd(out, s * (1.0f / (float)NBATCH));
    }
}

extern "C" void kernel_launch(void* const* d_in, const int* in_sizes, int n_in,
                              void* d_out, int out_size, void* d_ws, size_t ws_size,
                              hipStream_t stream) {
    const float* pred  = (const float*)d_in[0];
    const float* label = (const float*)d_in[1];
    float* out = (float*)d_out;

    hipMemsetAsync(out, 0, sizeof(float), stream);

    const int grid = NBATCH / NB;  // 4096 blocks, exact
    yolo_loss_kernel<<<grid, BLOCK, 0, stream>>>(pred, label, out);
}

// Round 4
// 204.389 us; speedup vs baseline: 1.0707x; 1.0707x over previous
//
#include <hip/hip_runtime.h>

// YOLOv1 loss: pred/label (16384, 30, 7, 7) fp32 -> scalar.
// R3: (a) kill same-address atomicAdd chain (R0/R2 durations scale with
//     atomic count at ~21ns each -> serialization tail). Per-block partials
//     to d_ws + tiny reduce kernel instead.
//     (b) LDS staging with NB=2 (23.5KB -> 6 blocks/CU) for overlap.

#define NBATCH 16384
#define NCH 30
#define NCELL 49       // 7*7
#define BSTRIDE 1470   // 30*49
#define BLOCK 256
#define NB 2           // batches per block
#define CHUNK (NB * BSTRIDE)   // 2940 floats per tensor per block
#define CHUNK4 (CHUNK / 4)     // 735 float4 (exact)
#define NBLOCKS (NBATCH / NB)  // 8192

__device__ __forceinline__ float sq(float x) { return x * x; }

__device__ __forceinline__ float iou_vs_label(float x, float y, float w, float h,
                                              float fc, float fr,
                                              float lx1, float ly1, float lx2, float ly2,
                                              float larea) {
    const float inv7 = 1.0f / 7.0f;
    float cx = (x + fc) * inv7;
    float cy = (y + fr) * inv7;
    float hw = w * 0.5f, hh = h * 0.5f;
    float x1 = cx - hw, y1 = cy - hh;
    float x2 = cx + hw, y2 = cy + hh;
    float iw = fmaxf(fminf(x2, lx2) - fmaxf(x1, lx1), 0.0f);
    float ih = fmaxf(fminf(y2, ly2) - fmaxf(y1, ly1), 0.0f);
    float inter = iw * ih;
    float area = (x2 - x1) * (y2 - y1);
    return inter / (area + larea - inter + 1e-10f);
}

__global__ __launch_bounds__(BLOCK) void yolo_loss_main(const float* __restrict__ pred,
                                                        const float* __restrict__ label,
                                                        float* __restrict__ partials) {
    __shared__ float4 sp4[CHUNK4];
    __shared__ float4 sl4[CHUNK4];

    const int blk = blockIdx.x;

    // ---- Stage: contiguous, coalesced, fully independent float4 copies ----
    {
        const float4* gp = (const float4*)(pred + (size_t)blk * CHUNK);
        const float4* gl = (const float4*)(label + (size_t)blk * CHUNK);
#pragma unroll
        for (int it = 0; it < 3; ++it) {
            int i = it * BLOCK + threadIdx.x;
            if (i < CHUNK4) {
                sp4[i] = gp[i];
                sl4[i] = gl[i];
            }
        }
    }
    __syncthreads();

    // ---- Compute: 98 threads = 2 batches x 49 cells, reads from LDS ----
    float per_cell = 0.0f;
    if (threadIdx.x < NB * NCELL) {
        const int lb = threadIdx.x / NCELL;
        const int rc = threadIdx.x - lb * NCELL;
        const int r = rc / 7;
        const int c = rc - r * 7;

        const float* sp = (const float*)sp4 + lb * BSTRIDE + rc;
        const float* sl = (const float*)sl4 + lb * BSTRIDE + rc;

        float p[NCH], l[NCH];
#pragma unroll
        for (int ch = 0; ch < NCH; ++ch) {
            p[ch] = sp[ch * NCELL];
            l[ch] = sl[ch * NCELL];
        }

        const float fc = (float)c, fr = (float)r;
        const float inv7 = 1.0f / 7.0f;

        float lcx = (l[0] + fc) * inv7;
        float lcy = (l[1] + fr) * inv7;
        float lhw = l[2] * 0.5f, lhh = l[3] * 0.5f;
        float lx1 = lcx - lhw, ly1 = lcy - lhh;
        float lx2 = lcx + lhw, ly2 = lcy + lhh;
        float larea = (lx2 - lx1) * (ly2 - ly1);

        float iou1 = iou_vs_label(p[0], p[1], p[2], p[3], fc, fr, lx1, ly1, lx2, ly2, larea);
        float iou2 = iou_vs_label(p[5], p[6], p[7], p[8], fc, fr, lx1, ly1, lx2, ly2, larea);
        bool choose1 = iou1 >= iou2;

        float coord1 = 5.0f * (sq(p[0] - l[0]) + sq(p[1] - l[1]))
                     + sq(sqrtf(p[2]) - sqrtf(l[2])) + sq(sqrtf(p[3]) - sqrtf(l[3]));
        float coord2 = 5.0f * (sq(p[5] - l[5]) + sq(p[6] - l[6]))
                     + sq(sqrtf(p[7]) - sqrtf(l[7])) + sq(sqrtf(p[8]) - sqrtf(l[8]));

        float obj1 = sq(p[4] - iou1);
        float obj2 = sq(p[9] - iou2);

        float coord      = choose1 ? coord1 : coord2;
        float obj_conf   = choose1 ? obj1 : obj2;
        float noobj_conf = 0.5f * (choose1 ? obj2 : obj1);

        float class_l = 0.0f;
#pragma unroll
        for (int ch = 10; ch < NCH; ++ch) class_l += sq(p[ch] - l[ch]);

        float obj_cell = coord + obj_conf + noobj_conf + class_l;
        float psum = p[4] + p[9];
        float noobj_cell = 0.5f * psum * psum;

        per_cell = (l[4] == 1.0f) ? obj_cell : noobj_cell;
    }

    // ---- Reduce within block -> plain store of partial (NO atomics) ----
    float v = per_cell;
#pragma unroll
    for (int off = 32; off > 0; off >>= 1) v += __shfl_down(v, off, 64);

    __shared__ float smem[BLOCK / 64];
    const int lane = threadIdx.x & 63;
    const int wave = threadIdx.x >> 6;
    if (lane == 0) smem[wave] = v;
    __syncthreads();
    if (threadIdx.x == 0) {
        partials[blk] = smem[0] + smem[1] + smem[2] + smem[3];
    }
}

__global__ __launch_bounds__(BLOCK) void yolo_loss_reduce(const float* __restrict__ partials,
                                                          float* __restrict__ out) {
    float s = 0.0f;
#pragma unroll
    for (int it = 0; it < NBLOCKS / BLOCK; ++it)   // 32 independent loads
        s += partials[it * BLOCK + threadIdx.x];

#pragma unroll
    for (int off = 32; off > 0; off >>= 1) s += __shfl_down(s, off, 64);

    __shared__ float smem[BLOCK / 64];
    const int lane = threadIdx.x & 63;
    const int wave = threadIdx.x >> 6;
    if (lane == 0) smem[wave] = s;
    __syncthreads();
    if (threadIdx.x == 0) {
        out[0] = (smem[0] + smem[1] + smem[2] + smem[3]) * (1.0f / (float)NBATCH);
    }
}

extern "C" void kernel_launch(void* const* d_in, const int* in_sizes, int n_in,
                              void* d_out, int out_size, void* d_ws, size_t ws_size,
                              hipStream_t stream) {
    const float* pred  = (const float*)d_in[0];
    const float* label = (const float*)d_in[1];
    float* out = (float*)d_out;
    float* partials = (float*)d_ws;   // 8192 floats = 32 KB scratch

    yolo_loss_main<<<NBLOCKS, BLOCK, 0, stream>>>(pred, label, partials);
    yolo_loss_reduce<<<1, BLOCK, 0, stream>>>(partials, out);
}